// Round 14
// baseline (492.657 us; speedup 1.0000x reference)
//
#include <hip/hip_runtime.h>

// SelfAttention (Transformer-XL style) on gfx950.
// conv3 (all converts fused; dw_bf relocated, no alias), GEMM1 split into
// exact-round launches (NF=4 for N 0..8191 + NF=2 for N 8192..12287),
// vectorized RoPE preps, flash attn (swapped-QK lane-local softmax), gemmT NF=2.

typedef __attribute__((ext_vector_type(4))) float f32x4;
typedef __attribute__((ext_vector_type(8))) short bf16x8;
typedef unsigned short u16;

#define SQ   1024
#define BSZ  2
#define H    4096
#define NH   32
#define HD   128
#define MEML 1024
#define KV   2048

__device__ __forceinline__ u16 f32_to_bf16(float f) {
  union { float f; unsigned int u; } v; v.f = f;
  unsigned int r = v.u + 0x7FFFu + ((v.u >> 16) & 1u);
  return (u16)(r >> 16);
}
__device__ __forceinline__ float bf16_to_f32(u16 x) {
  union { unsigned int u; float f; } v; v.u = ((unsigned int)x) << 16; return v.f;
}

__device__ __forceinline__ void gload_lds16(const void* g, void* l) {
  __builtin_amdgcn_global_load_lds((const __attribute__((address_space(1))) void*)g,
                                   (__attribute__((address_space(3))) void*)l, 16, 0, 0);
}

// ---------------- fused f32 -> bf16 convert (hidden, qkv_w, dense_w) ----------------
#define NA4 2097152
#define NB4 12582912
#define NC4 4194304
__global__ __launch_bounds__(256) void conv3(const float* __restrict__ a, u16* __restrict__ oa,
                                             const float* __restrict__ bsrc, u16* __restrict__ ob,
                                             const float* __restrict__ csrc, u16* __restrict__ oc) {
  int idx = blockIdx.x * 256 + threadIdx.x;
  const float* s; u16* o; int off;
  if (idx < NA4)            { s = a;    o = oa; off = idx; }
  else if (idx < NA4 + NB4) { s = bsrc; o = ob; off = idx - NA4; }
  else                      { s = csrc; o = oc; off = idx - (NA4 + NB4); }
  float4 v = ((const float4*)s)[off];
  ushort4 r;
  r.x = f32_to_bf16(v.x); r.y = f32_to_bf16(v.y);
  r.z = f32_to_bf16(v.z); r.w = f32_to_bf16(v.w);
  ((ushort4*)o)[off] = r;
}

// ---------------- RoPE tables ----------------
__global__ __launch_bounds__(256) void rope_tables(float* __restrict__ cost, float* __restrict__ sint) {
  int idx = blockIdx.x * 256 + threadIdx.x;   // 65536 = 1024 s * 64 j
  int s = idx >> 6, j = idx & 63;
  float inv = powf(10000.0f, -(float)j / 64.0f);
  float ang = (float)(MEML + s) * inv;
  cost[idx] = cosf(ang);
  sint[idx] = sinf(ang);
}

// ---------------- GEMM: C[M,N] = A[M,K](bf16) * B[N,K]^T(bf16) + bias[N] ----------
// BM=256, BN=NF*64, BK=64; 512 threads = 8 waves (2M x 4N), per-wave 128 x NF*16.
// 4 phases/K-tile; 8KiB stage units; counted vmcnt(NF) once per tile.
// n_base: column offset of this launch's N-panel (for split GEMM1).
template <typename OUT_T, int NF>
__global__ __launch_bounds__(512, 2) void gemmT(const u16* __restrict__ A, const u16* __restrict__ B,
                                                const float* __restrict__ bias, OUT_T* __restrict__ C,
                                                int N, int K, int n_base) {
  constexpr int WN = NF * 16;                 // per-wave N width
  constexpr int NH0 = (NF + 1) / 2;           // frags in set0
  constexpr int SB2 = NF - (NF >> 1);         // B units staged at ph2
  __shared__ char lds[2][32768 + NF * 8192];  // A rows 0..255 @0, B rows @32768
  const int tid = threadIdx.x;
  const int lane = tid & 63;
  const int w = tid >> 6;
  const int wm = w >> 2, wn = w & 3;
  const int rl = lane & 15, cg = lane >> 4;
  const int m0 = blockIdx.y * 256, n0 = n_base + blockIdx.x * (NF * 64);
  const int nt = K >> 6;

  const int srow = tid >> 3;                              // 0..63 (unit-local row)
  const int scb = ((tid & 7) << 4) ^ ((srow & 7) << 4);   // pre-swizzled source byte col

  auto stage_a = [&](int tile, int ua) {
    if (tile >= nt) return;
    gload_lds16((const char*)(A + (size_t)(m0 + ua * 64 + srow) * K + (size_t)tile * 64) + scb,
                lds[tile & 1] + ua * 8192 + tid * 16);
  };
  auto stage_b = [&](int tile, int ub) {
    if (tile >= nt) return;
    gload_lds16((const char*)(B + (size_t)(n0 + ub * 64 + srow) * K + (size_t)tile * 64) + scb,
                lds[tile & 1] + 32768 + ub * 8192 + tid * 16);
  };

  f32x4 acc[8][NF];
#pragma unroll
  for (int i = 0; i < 8; ++i)
#pragma unroll
    for (int j = 0; j < NF; ++j) acc[i][j] = (f32x4){0.f, 0.f, 0.f, 0.f};

  bf16x8 af[4][2], bf[NF][2];

  auto read_a = [&](const char* buf, int mh) {
#pragma unroll
    for (int mi = 0; mi < 4; ++mi) {
      int R = wm * 128 + mh * 64 + mi * 16 + rl;
#pragma unroll
      for (int kk = 0; kk < 2; ++kk) {
        int cb = (kk * 64 + cg * 16) ^ ((R & 7) << 4);
        af[mi][kk] = *(const bf16x8*)(buf + R * 128 + cb);
      }
    }
  };
  auto read_b1 = [&](const char* buf, int nl) {
    int R = wn * WN + nl * 16 + rl;
#pragma unroll
    for (int kk = 0; kk < 2; ++kk) {
      int cb = (kk * 64 + cg * 16) ^ ((R & 7) << 4);
      bf[nl][kk] = *(const bf16x8*)(buf + 32768 + R * 128 + cb);
    }
  };
  auto mfset = [&](int mh, int lo, int hi) {
    __builtin_amdgcn_s_setprio(1);
#pragma unroll
    for (int kk = 0; kk < 2; ++kk)
#pragma unroll
      for (int mi = 0; mi < 4; ++mi)
#pragma unroll
        for (int nl = 0; nl < NF; ++nl)
          if (nl >= lo && nl < hi)
            acc[mh * 4 + mi][nl] = __builtin_amdgcn_mfma_f32_16x16x32_bf16(
                af[mi][kk], bf[nl][kk], acc[mh * 4 + mi][nl], 0, 0, 0);
    __builtin_amdgcn_s_setprio(0);
  };

  // prologue: tile0 A+B, tile1 B; wait tile0 landed (tile1.B = NF outstanding)
#pragma unroll
  for (int ua = 0; ua < 4; ++ua) stage_a(0, ua);
#pragma unroll
  for (int ub = 0; ub < NF; ++ub) stage_b(0, ub);
#pragma unroll
  for (int ub = 0; ub < NF; ++ub) stage_b(1, ub);
  if (NF == 2)      { asm volatile("s_waitcnt vmcnt(2)" ::: "memory"); }
  else if (NF == 3) { asm volatile("s_waitcnt vmcnt(3)" ::: "memory"); }
  else              { asm volatile("s_waitcnt vmcnt(4)" ::: "memory"); }
  __builtin_amdgcn_s_barrier();

  for (int kt = 0; kt < nt; ++kt) {
    const char* buf = lds[kt & 1];
    // ph0: quadrant (mh0,set0); stage (kt+1).A units 0,1 -> p^1
    read_a(buf, 0);
#pragma unroll
    for (int nl = 0; nl < NH0; ++nl) read_b1(buf, nl);
    stage_a(kt + 1, 0); stage_a(kt + 1, 1);
    __builtin_amdgcn_s_barrier();
    asm volatile("s_waitcnt lgkmcnt(0)" ::: "memory");
    mfset(0, 0, NH0);
    __builtin_amdgcn_s_barrier();
    // ph1: quadrant (mh0,set1); stage (kt+1).A units 2,3 -> p^1
#pragma unroll
    for (int nl = NH0; nl < NF; ++nl) read_b1(buf, nl);
    stage_a(kt + 1, 2); stage_a(kt + 1, 3);
    __builtin_amdgcn_s_barrier();
    asm volatile("s_waitcnt lgkmcnt(0)" ::: "memory");
    mfset(0, NH0, NF);
    __builtin_amdgcn_s_barrier();
    // ph2: quadrant (mh1,set1); stage (kt+2).B units 0..SB2-1 -> p
    read_a(buf, 1);
#pragma unroll
    for (int ub = 0; ub < SB2; ++ub) stage_b(kt + 2, ub);
    __builtin_amdgcn_s_barrier();
    asm volatile("s_waitcnt lgkmcnt(0)" ::: "memory");
    mfset(1, NH0, NF);
    __builtin_amdgcn_s_barrier();
    // ph3: quadrant (mh1,set0); stage (kt+2).B units SB2..NF-1 -> p; counted vmcnt
#pragma unroll
    for (int ub = SB2; ub < NF; ++ub) stage_b(kt + 2, ub);
    __builtin_amdgcn_s_barrier();
    mfset(1, 0, NH0);
    if (kt + 2 < nt) {
      if (NF == 2)      { asm volatile("s_waitcnt vmcnt(2)" ::: "memory"); }
      else if (NF == 3) { asm volatile("s_waitcnt vmcnt(3)" ::: "memory"); }
      else              { asm volatile("s_waitcnt vmcnt(4)" ::: "memory"); }
    } else if (kt + 1 < nt) {
      asm volatile("s_waitcnt vmcnt(0)" ::: "memory");
    }
    __builtin_amdgcn_s_barrier();
  }

  // epilogue: C layout col=lane&15, row=(lane>>4)*4+j
#pragma unroll
  for (int ni = 0; ni < NF; ++ni) {
    int col = n0 + wn * WN + ni * 16 + rl;
    float bv = bias[col];
#pragma unroll
    for (int mi = 0; mi < 8; ++mi) {
      int rbase = m0 + wm * 128 + mi * 16 + cg * 4;
#pragma unroll
      for (int j = 0; j < 4; ++j) {
        float v = acc[mi][ni][j] + bv;
        if constexpr (sizeof(OUT_T) == 2)
          C[(size_t)(rbase + j) * N + col] = (OUT_T)f32_to_bf16(v);
        else
          C[(size_t)(rbase + j) * N + col] = (OUT_T)v;
      }
    }
  }
}

// ---------------- prep: roped Q (scaled) and roped new-K (vectorized) ----------
__global__ __launch_bounds__(256) void prep_qk(const u16* __restrict__ mixed,
                                               const float* __restrict__ cost,
                                               const float* __restrict__ sint,
                                               u16* __restrict__ Qb, u16* __restrict__ Kb) {
  int s0 = blockIdx.x * 64, head = blockIdx.y;
  int b = head >> 5, nh = head & 31;
  int tid = threadIdx.x;
  const float qs = 0.08838834764831845f;  // 1/sqrt(128)
#pragma unroll
  for (int i = 0; i < 4; ++i) {
    int flat = i * 256 + tid;           // 1024 = 64 s * 16 j-groups
    int sl = flat >> 4, jg = (flat & 15) << 2;
    int s = s0 + sl;
    size_t base = ((size_t)(s * 2 + b)) * 12288 + (size_t)nh * 384;
    ushort4 q1v = *(const ushort4*)(mixed + base + jg);
    ushort4 q2v = *(const ushort4*)(mixed + base + 64 + jg);
    ushort4 k1v = *(const ushort4*)(mixed + base + 128 + jg);
    ushort4 k2v = *(const ushort4*)(mixed + base + 192 + jg);
    float4 cv = *(const float4*)(cost + s * 64 + jg);
    float4 sv = *(const float4*)(sint + s * 64 + jg);
    const u16* q1a = (const u16*)&q1v; const u16* q2a = (const u16*)&q2v;
    const u16* k1a = (const u16*)&k1v; const u16* k2a = (const u16*)&k2v;
    const float* ca = (const float*)&cv; const float* sa = (const float*)&sv;
    ushort4 qo1, qo2, ko1, ko2;
    u16* qo1a = (u16*)&qo1; u16* qo2a = (u16*)&qo2;
    u16* ko1a = (u16*)&ko1; u16* ko2a = (u16*)&ko2;
#pragma unroll
    for (int e = 0; e < 4; ++e) {
      float q1 = bf16_to_f32(q1a[e]), q2 = bf16_to_f32(q2a[e]);
      float k1 = bf16_to_f32(k1a[e]), k2 = bf16_to_f32(k2a[e]);
      float c = ca[e], sn = sa[e];
      qo1a[e] = f32_to_bf16((q1 * c - q2 * sn) * qs);
      qo2a[e] = f32_to_bf16((q2 * c + q1 * sn) * qs);
      ko1a[e] = f32_to_bf16(k1 * c - k2 * sn);
      ko2a[e] = f32_to_bf16(k2 * c + k1 * sn);
    }
    size_t qoff = ((size_t)head * SQ + s) * HD;
    *(ushort4*)(Qb + qoff + jg)      = qo1;
    *(ushort4*)(Qb + qoff + 64 + jg) = qo2;
    size_t koff = ((size_t)head * KV + MEML + s) * HD;
    *(ushort4*)(Kb + koff + jg)      = ko1;
    *(ushort4*)(Kb + koff + 64 + jg) = ko2;
  }
}

// ---------------- prep: mem-K copy + V transposed per head (vectorized) ----------------
__global__ __launch_bounds__(256) void prep_kv(const u16* __restrict__ mixed,
                                               const float* __restrict__ mem,
                                               u16* __restrict__ Kb, u16* __restrict__ Vtb) {
  int t0 = blockIdx.x * 64, head = blockIdx.y;
  int b = head >> 5, nh = head & 31;
  __shared__ u16 vt[128 * 72];
  int tid = threadIdx.x;
  if (t0 < MEML) {
#pragma unroll
    for (int i = 0; i < 8; ++i) {       // 2048 = 64 t * 32 d-groups
      int flat = i * 256 + tid;
      int tl = flat >> 5, dg = (flat & 31) << 2;
      float4 kv4 = *(const float4*)(mem + ((size_t)b * MEML + t0 + tl) * 8192 + (size_t)nh * HD + dg);
      ushort4 o;
      o.x = f32_to_bf16(kv4.x); o.y = f32_to_bf16(kv4.y);
      o.z = f32_to_bf16(kv4.z); o.w = f32_to_bf16(kv4.w);
      *(ushort4*)(Kb + ((size_t)head * KV + t0 + tl) * HD + dg) = o;
    }
  }
#pragma unroll
  for (int i = 0; i < 8; ++i) {
    int flat = i * 256 + tid;
    int tl = flat >> 5, dg = (flat & 31) << 2;
    int t = t0 + tl;
    u16 e0, e1, e2, e3;
    if (t < MEML) {
      float4 v4 = *(const float4*)(mem + ((size_t)b * MEML + t) * 8192 + 4096 + (size_t)nh * HD + dg);
      e0 = f32_to_bf16(v4.x); e1 = f32_to_bf16(v4.y);
      e2 = f32_to_bf16(v4.z); e3 = f32_to_bf16(v4.w);
    } else {
      ushort4 v4 = *(const ushort4*)(mixed + ((size_t)((t - MEML) * 2 + b)) * 12288 + (size_t)nh * 384 + 256 + dg);
      e0 = v4.x; e1 = v4.y; e2 = v4.z; e3 = v4.w;
    }
    vt[(dg + 0) * 72 + tl] = e0;
    vt[(dg + 1) * 72 + tl] = e1;
    vt[(dg + 2) * 72 + tl] = e2;
    vt[(dg + 3) * 72 + tl] = e3;
  }
  __syncthreads();
#pragma unroll
  for (int i = 0; i < 4; ++i) {
    int c = i * 256 + tid;
    int d = c >> 3, slot = c & 7;
    *(bf16x8*)(Vtb + ((size_t)head * HD + d) * KV + t0 + slot * 8) =
        *(const bf16x8*)(vt + d * 72 + slot * 8);
  }
}

// ---------------- flash attention: SWAPPED-QK, lane-local softmax ----------------
__global__ __launch_bounds__(512) void attn_fwd(const u16* __restrict__ Qb, const u16* __restrict__ Kb,
                                                const u16* __restrict__ Vtb, u16* __restrict__ ctx) {
  __shared__ u16 Ks[2][64 * 128];    // [buf][t][k]; reused as T[128][128] in epilogue
  __shared__ u16 Vts[2][128 * 64];   // [buf][d][t]
  __shared__ u16 Ps[8 * 16 * 64];    // per-wave P: [s=rl row][t], XOR-swizzled
  const int tid = threadIdx.x;
  const int lane = tid & 63;
  const int w = tid >> 6;            // 0..7
  const int q0 = blockIdx.x * 128;
  const int head = blockIdx.y;
  const int rl = lane & 15, cg = lane >> 4;
  const int sglob = q0 + w * 16 + rl;   // this lane's query row

  bf16x8 qf[4];
  {
    const u16* Qrow = Qb + ((size_t)head * SQ + sglob) * HD;
#pragma unroll
    for (int kk = 0; kk < 4; ++kk)
      qf[kk] = *(const bf16x8*)(Qrow + kk * 32 + cg * 8);
  }

  f32x4 acc[8];
#pragma unroll
  for (int i = 0; i < 8; ++i) acc[i] = (f32x4){0.f, 0.f, 0.f, 0.f};
  float mrow = -3.0e38f;
  float lrow = 0.f;

  const int ntile = (MEML + q0 + 128) >> 6;   // 18..32

  auto stageKV = [&](int it) {
    int t0 = it * 64;
    int buf = it & 1;
#pragma unroll
    for (int i = 0; i < 2; ++i) {
      int flat = i * 512 + tid;
      int row = flat >> 4;
      int scb = ((flat & 15) << 4) ^ ((row & 7) << 4);
      gload_lds16((const char*)(Kb + ((size_t)head * KV + t0 + row) * HD) + scb,
                  (char*)Ks[buf] + (flat << 4));
    }
#pragma unroll
    for (int i = 0; i < 2; ++i) {
      int flat = i * 512 + tid;
      int row = flat >> 3;
      int scb = ((flat & 7) << 4) ^ ((row & 7) << 4);
      gload_lds16((const char*)(Vtb + ((size_t)head * HD + row) * KV + t0) + scb,
                  (char*)Vts[buf] + (flat << 4));
    }
  };

  stageKV(0);

  for (int it = 0; it < ntile; ++it) {
    const int t0 = it * 64;
    if (it + 1 < ntile) {
      stageKV(it + 1);
      asm volatile("s_waitcnt vmcnt(4)" ::: "memory");
    } else {
      asm volatile("s_waitcnt vmcnt(0)" ::: "memory");
    }
    __builtin_amdgcn_s_barrier();
    const char* Kbuf = (const char*)Ks[it & 1];
    const char* Vbuf = (const char*)Vts[it & 1];
    const bool live = (t0 - MEML) <= (q0 + w * 16 + 15);
    if (live) {
      // S^T = K Q^T : lane holds S[t=t0+tn*16+cg*4+j][s=sglob]
      f32x4 sf[4];
#pragma unroll
      for (int tn = 0; tn < 4; ++tn) {
        f32x4 s = (f32x4){0.f, 0.f, 0.f, 0.f};
#pragma unroll
        for (int kk = 0; kk < 4; ++kk) {
          int row = tn * 16 + rl;
          int cb = (kk * 64 + cg * 16) ^ ((row & 7) << 4);
          bf16x8 kf = *(const bf16x8*)(Kbuf + row * 256 + cb);
          s = __builtin_amdgcn_mfma_f32_16x16x32_bf16(kf, qf[kk], s, 0, 0, 0);
        }
        sf[tn] = s;
      }
      if (t0 + 63 > MEML + q0 + w * 16) {
#pragma unroll
        for (int tn = 0; tn < 4; ++tn)
#pragma unroll
          for (int j = 0; j < 4; ++j) {
            int t = t0 + tn * 16 + cg * 4 + j;
            if (t - MEML > sglob) sf[tn][j] = -40000.0f;
          }
      }
      // in-lane max over 16 t-values, then 2-shfl allreduce across cg
      float mt = sf[0][0];
#pragma unroll
      for (int tn = 0; tn < 4; ++tn)
#pragma unroll
        for (int j = 0; j < 4; ++j) mt = fmaxf(mt, sf[tn][j]);
      mt = fmaxf(mt, __shfl_xor(mt, 16, 64));
      mt = fmaxf(mt, __shfl_xor(mt, 32, 64));
      float mn = fmaxf(mrow, mt);
      float psc = __expf(mrow - mn);
      mrow = mn;
      float ls = 0.f;
#pragma unroll
      for (int tn = 0; tn < 4; ++tn) {
        ushort4 pk;
        u16* pka = (u16*)&pk;
#pragma unroll
        for (int j = 0; j < 4; ++j) {
          float p = __expf(sf[tn][j] - mn);
          ls += p;
          pka[j] = f32_to_bf16(p);
        }
        int addr = w * 2048 + rl * 128 + ((tn * 32 + cg * 8) ^ ((rl & 7) << 4));
        *(ushort4*)((char*)Ps + addr) = pk;
      }
      ls += __shfl_xor(ls, 16, 64);
      ls += __shfl_xor(ls, 32, 64);
      lrow = lrow * psc + ls;
#pragma unroll
      for (int dn = 0; dn < 8; ++dn)
#pragma unroll
        for (int j = 0; j < 4; ++j) acc[dn][j] *= psc;
      // ctx^T += V^T P^T : A=Vt rows=d, B=P rows(s)=rl
#pragma unroll
      for (int dn = 0; dn < 8; ++dn) {
#pragma unroll
        for (int kk2 = 0; kk2 < 2; ++kk2) {
          int pcb = (kk2 * 64 + cg * 16) ^ ((rl & 7) << 4);
          bf16x8 pf = *(const bf16x8*)((const char*)Ps + w * 2048 + rl * 128 + pcb);
          int vrow = dn * 16 + rl;
          int vcb = (kk2 * 64 + cg * 16) ^ ((vrow & 7) << 4);
          bf16x8 vf = *(const bf16x8*)(Vbuf + vrow * 128 + vcb);
          acc[dn] = __builtin_amdgcn_mfma_f32_16x16x32_bf16(vf, pf, acc[dn], 0, 0, 0);
        }
      }
    }
    __builtin_amdgcn_s_barrier();
  }

  // epilogue: acc holds ctx^T[d][s] -> transpose via LDS (reuse Ks, 32 KB) for
  // coalesced 16B global stores. T layout: [128 s-local][128 d] bf16, 256B rows.
  const float inv = 1.0f / lrow;
  u16* T = (u16*)Ks;
  {
    int trow = w * 16 + rl;           // trow&7 == rl&7
#pragma unroll
    for (int dn = 0; dn < 8; ++dn) {
      ushort4 pk;
      u16* pka = (u16*)&pk;
#pragma unroll
      for (int j = 0; j < 4; ++j) pka[j] = f32_to_bf16(acc[dn][j] * inv);
      int addr = trow * 256 + ((dn * 32 + cg * 8) ^ ((rl & 7) << 4));
      *(ushort4*)((char*)T + addr) = pk;
    }
  }
  asm volatile("s_waitcnt lgkmcnt(0)" ::: "memory");
  __builtin_amdgcn_s_barrier();
  const int b = head >> 5, nh = head & 31;
#pragma unroll
  for (int i = 0; i < 4; ++i) {
    int flat = i * 512 + tid;         // 2048 chunks of 16B (128 rows x 16 chunks)
    int r = flat >> 4, c = flat & 15;
    bf16x8 v = *(const bf16x8*)((const char*)T + r * 256 + ((c * 16) ^ ((r & 7) << 4)));
    *(bf16x8*)(ctx + ((size_t)((q0 + r) * 2 + b)) * H + (size_t)nh * HD + c * 8) = v;
  }
}

// ---------------- launch ----------------
extern "C" void kernel_launch(void* const* d_in, const int* in_sizes, int n_in,
                              void* d_out, int out_size, void* d_ws, size_t ws_size,
                              hipStream_t stream) {
  const float* hidden  = (const float*)d_in[0];
  const float* mem     = (const float*)d_in[3];
  const float* qkv_w   = (const float*)d_in[4];
  const float* qkv_b   = (const float*)d_in[5];
  const float* dense_w = (const float*)d_in[6];
  const float* dense_b = (const float*)d_in[7];
  float* out = (float*)d_out;
  char* ws = (char*)d_ws;

  u16* mixed = (u16*)ws;                          // [0, 50331648) bf16 2048x12288
  u16* dw_bf = (u16*)(ws + 50331648);             // [50331648, 83886080) -- NO alias now
  char* R1 = ws + 100663296;
  u16* hid_bf = (u16*)R1;                         // aliased: pre-GEMM1 use
  u16* qw_bf  = (u16*)(R1 + 16777216);            // 100 MB; consumed by gemm1
  u16* Qb  = (u16*)R1;
  u16* Kb  = (u16*)(R1 + 16777216);
  u16* Vtb = (u16*)(R1 + 50331648);
  u16* ctx = (u16*)(R1 + 83886080);
  float* cost = (float*)(ws + 234881024);
  float* sint = (float*)(ws + 234881024 + 262144);

  conv3<<<73728, 256, 0, stream>>>(hidden, hid_bf, qkv_w, qw_bf, dense_w, dw_bf);
  rope_tables<<<256, 256, 0, stream>>>(cost, sint);
  // GEMM1 split into exact-round launches: N 0..8191 (NF=4), N 8192..12287 (NF=2)
  gemmT<u16, 4><<<dim3(32, 8), 512, 0, stream>>>(hid_bf, qw_bf, qkv_b, mixed, 12288, 4096, 0);
  gemmT<u16, 2><<<dim3(32, 8), 512, 0, stream>>>(hid_bf, qw_bf, qkv_b, mixed, 12288, 4096, 8192);
  prep_qk<<<dim3(16, 64), 256, 0, stream>>>(mixed, cost, sint, Qb, Kb);
  prep_kv<<<dim3(32, 64), 256, 0, stream>>>(mixed, mem, Kb, Vtb);
  attn_fwd<<<dim3(8, 64), 512, 0, stream>>>(Qb, Kb, Vtb, ctx);
  gemmT<float, 2><<<dim3(32, 8), 512, 0, stream>>>(ctx, dw_bf, dense_b, out, 4096, 4096, 0);
}

// Round 15
// 485.053 us; speedup vs baseline: 1.0157x; 1.0157x over previous
//
#include <hip/hip_runtime.h>

// SelfAttention (Transformer-XL style) on gfx950. FINAL = r13 config + merged preps.
// conv2 (hidden+qkv_w fused), gemmT NF=3 (qkv), conv(dense_w) AFTER gemm1 (alias),
// merged vectorized RoPE preps (one launch), flash attn (swapped-QK lane-local
// softmax, packed P, LDS-transpose epilogue), gemmT NF=2 (dense).

typedef __attribute__((ext_vector_type(4))) float f32x4;
typedef __attribute__((ext_vector_type(8))) short bf16x8;
typedef unsigned short u16;

#define SQ   1024
#define BSZ  2
#define H    4096
#define NH   32
#define HD   128
#define MEML 1024
#define KV   2048

__device__ __forceinline__ u16 f32_to_bf16(float f) {
  union { float f; unsigned int u; } v; v.f = f;
  unsigned int r = v.u + 0x7FFFu + ((v.u >> 16) & 1u);
  return (u16)(r >> 16);
}
__device__ __forceinline__ float bf16_to_f32(u16 x) {
  union { unsigned int u; float f; } v; v.u = ((unsigned int)x) << 16; return v.f;
}

__device__ __forceinline__ void gload_lds16(const void* g, void* l) {
  __builtin_amdgcn_global_load_lds((const __attribute__((address_space(1))) void*)g,
                                   (__attribute__((address_space(3))) void*)l, 16, 0, 0);
}

// ---------------- f32 -> bf16 convert (single buffer) ----------------
__global__ __launch_bounds__(256) void conv_bf16(const float* __restrict__ in,
                                                 u16* __restrict__ out, int n4) {
  int idx = blockIdx.x * 256 + threadIdx.x;
  if (idx < n4) {
    float4 v = ((const float4*)in)[idx];
    ushort4 o;
    o.x = f32_to_bf16(v.x); o.y = f32_to_bf16(v.y);
    o.z = f32_to_bf16(v.z); o.w = f32_to_bf16(v.w);
    ((ushort4*)out)[idx] = o;
  }
}

// ---------------- fused f32 -> bf16 convert (hidden + qkv_w only) ----------------
// dense_w NOT fused: dw_bf aliases qw_bf tail; converted after gemm1 (r10 lesson).
#define NA4 2097152
#define NB4 12582912
__global__ __launch_bounds__(256) void conv2(const float* __restrict__ a, u16* __restrict__ oa,
                                             const float* __restrict__ bsrc, u16* __restrict__ ob) {
  int idx = blockIdx.x * 256 + threadIdx.x;
  const float* s; u16* o; int off;
  if (idx < NA4) { s = a;    o = oa; off = idx; }
  else           { s = bsrc; o = ob; off = idx - NA4; }
  float4 v = ((const float4*)s)[off];
  ushort4 r;
  r.x = f32_to_bf16(v.x); r.y = f32_to_bf16(v.y);
  r.z = f32_to_bf16(v.z); r.w = f32_to_bf16(v.w);
  ((ushort4*)o)[off] = r;
}

// ---------------- RoPE tables ----------------
__global__ __launch_bounds__(256) void rope_tables(float* __restrict__ cost, float* __restrict__ sint) {
  int idx = blockIdx.x * 256 + threadIdx.x;   // 65536 = 1024 s * 64 j
  int s = idx >> 6, j = idx & 63;
  float inv = powf(10000.0f, -(float)j / 64.0f);
  float ang = (float)(MEML + s) * inv;
  cost[idx] = cosf(ang);
  sint[idx] = sinf(ang);
}

// ---------------- GEMM: C[M,N] = A[M,K](bf16) * B[N,K]^T(bf16) + bias[N] ----------
// BM=256, BN=NF*64, BK=64; 512 threads = 8 waves (2M x 4N), per-wave 128 x NF*16.
// 4 phases/K-tile; 8KiB stage units; counted vmcnt(NF) once per tile.
template <typename OUT_T, int NF>
__global__ __launch_bounds__(512, 2) void gemmT(const u16* __restrict__ A, const u16* __restrict__ B,
                                                const float* __restrict__ bias, OUT_T* __restrict__ C,
                                                int N, int K) {
  constexpr int WN = NF * 16;                 // per-wave N width
  constexpr int NH0 = (NF + 1) / 2;           // frags in set0
  constexpr int SB2 = NF - (NF >> 1);         // B units staged at ph2
  __shared__ char lds[2][32768 + NF * 8192];  // A rows 0..255 @0, B rows @32768
  const int tid = threadIdx.x;
  const int lane = tid & 63;
  const int w = tid >> 6;
  const int wm = w >> 2, wn = w & 3;
  const int rl = lane & 15, cg = lane >> 4;
  const int m0 = blockIdx.y * 256, n0 = blockIdx.x * (NF * 64);
  const int nt = K >> 6;

  const int srow = tid >> 3;                              // 0..63 (unit-local row)
  const int scb = ((tid & 7) << 4) ^ ((srow & 7) << 4);   // pre-swizzled source byte col

  auto stage_a = [&](int tile, int ua) {
    if (tile >= nt) return;
    gload_lds16((const char*)(A + (size_t)(m0 + ua * 64 + srow) * K + (size_t)tile * 64) + scb,
                lds[tile & 1] + ua * 8192 + tid * 16);
  };
  auto stage_b = [&](int tile, int ub) {
    if (tile >= nt) return;
    gload_lds16((const char*)(B + (size_t)(n0 + ub * 64 + srow) * K + (size_t)tile * 64) + scb,
                lds[tile & 1] + 32768 + ub * 8192 + tid * 16);
  };

  f32x4 acc[8][NF];
#pragma unroll
  for (int i = 0; i < 8; ++i)
#pragma unroll
    for (int j = 0; j < NF; ++j) acc[i][j] = (f32x4){0.f, 0.f, 0.f, 0.f};

  bf16x8 af[4][2], bf[NF][2];

  auto read_a = [&](const char* buf, int mh) {
#pragma unroll
    for (int mi = 0; mi < 4; ++mi) {
      int R = wm * 128 + mh * 64 + mi * 16 + rl;
#pragma unroll
      for (int kk = 0; kk < 2; ++kk) {
        int cb = (kk * 64 + cg * 16) ^ ((R & 7) << 4);
        af[mi][kk] = *(const bf16x8*)(buf + R * 128 + cb);
      }
    }
  };
  auto read_b1 = [&](const char* buf, int nl) {
    int R = wn * WN + nl * 16 + rl;
#pragma unroll
    for (int kk = 0; kk < 2; ++kk) {
      int cb = (kk * 64 + cg * 16) ^ ((R & 7) << 4);
      bf[nl][kk] = *(const bf16x8*)(buf + 32768 + R * 128 + cb);
    }
  };
  auto mfset = [&](int mh, int lo, int hi) {
    __builtin_amdgcn_s_setprio(1);
#pragma unroll
    for (int kk = 0; kk < 2; ++kk)
#pragma unroll
      for (int mi = 0; mi < 4; ++mi)
#pragma unroll
        for (int nl = 0; nl < NF; ++nl)
          if (nl >= lo && nl < hi)
            acc[mh * 4 + mi][nl] = __builtin_amdgcn_mfma_f32_16x16x32_bf16(
                af[mi][kk], bf[nl][kk], acc[mh * 4 + mi][nl], 0, 0, 0);
    __builtin_amdgcn_s_setprio(0);
  };

  // prologue: tile0 A+B, tile1 B; wait tile0 landed (tile1.B = NF outstanding)
#pragma unroll
  for (int ua = 0; ua < 4; ++ua) stage_a(0, ua);
#pragma unroll
  for (int ub = 0; ub < NF; ++ub) stage_b(0, ub);
#pragma unroll
  for (int ub = 0; ub < NF; ++ub) stage_b(1, ub);
  if (NF == 2)      { asm volatile("s_waitcnt vmcnt(2)" ::: "memory"); }
  else if (NF == 3) { asm volatile("s_waitcnt vmcnt(3)" ::: "memory"); }
  else              { asm volatile("s_waitcnt vmcnt(4)" ::: "memory"); }
  __builtin_amdgcn_s_barrier();

  for (int kt = 0; kt < nt; ++kt) {
    const char* buf = lds[kt & 1];
    // ph0: quadrant (mh0,set0); stage (kt+1).A units 0,1 -> p^1
    read_a(buf, 0);
#pragma unroll
    for (int nl = 0; nl < NH0; ++nl) read_b1(buf, nl);
    stage_a(kt + 1, 0); stage_a(kt + 1, 1);
    __builtin_amdgcn_s_barrier();
    asm volatile("s_waitcnt lgkmcnt(0)" ::: "memory");
    mfset(0, 0, NH0);
    __builtin_amdgcn_s_barrier();
    // ph1: quadrant (mh0,set1); stage (kt+1).A units 2,3 -> p^1
#pragma unroll
    for (int nl = NH0; nl < NF; ++nl) read_b1(buf, nl);
    stage_a(kt + 1, 2); stage_a(kt + 1, 3);
    __builtin_amdgcn_s_barrier();
    asm volatile("s_waitcnt lgkmcnt(0)" ::: "memory");
    mfset(0, NH0, NF);
    __builtin_amdgcn_s_barrier();
    // ph2: quadrant (mh1,set1); stage (kt+2).B units 0..SB2-1 -> p
    read_a(buf, 1);
#pragma unroll
    for (int ub = 0; ub < SB2; ++ub) stage_b(kt + 2, ub);
    __builtin_amdgcn_s_barrier();
    asm volatile("s_waitcnt lgkmcnt(0)" ::: "memory");
    mfset(1, NH0, NF);
    __builtin_amdgcn_s_barrier();
    // ph3: quadrant (mh1,set0); stage (kt+2).B units SB2..NF-1 -> p; counted vmcnt
#pragma unroll
    for (int ub = SB2; ub < NF; ++ub) stage_b(kt + 2, ub);
    __builtin_amdgcn_s_barrier();
    mfset(1, 0, NH0);
    if (kt + 2 < nt) {
      if (NF == 2)      { asm volatile("s_waitcnt vmcnt(2)" ::: "memory"); }
      else if (NF == 3) { asm volatile("s_waitcnt vmcnt(3)" ::: "memory"); }
      else              { asm volatile("s_waitcnt vmcnt(4)" ::: "memory"); }
    } else if (kt + 1 < nt) {
      asm volatile("s_waitcnt vmcnt(0)" ::: "memory");
    }
    __builtin_amdgcn_s_barrier();
  }

  // epilogue: C layout col=lane&15, row=(lane>>4)*4+j
#pragma unroll
  for (int ni = 0; ni < NF; ++ni) {
    int col = n0 + wn * WN + ni * 16 + rl;
    float bv = bias[col];
#pragma unroll
    for (int mi = 0; mi < 8; ++mi) {
      int rbase = m0 + wm * 128 + mi * 16 + cg * 4;
#pragma unroll
      for (int j = 0; j < 4; ++j) {
        float v = acc[mi][ni][j] + bv;
        if constexpr (sizeof(OUT_T) == 2)
          C[(size_t)(rbase + j) * N + col] = (OUT_T)f32_to_bf16(v);
        else
          C[(size_t)(rbase + j) * N + col] = (OUT_T)v;
      }
    }
  }
}

// ---------------- merged prep: blocks 0..15 = roped Q/K, 16..47 = mem-K + Vt ------
__global__ __launch_bounds__(256) void prep_all(const u16* __restrict__ mixed,
                                                const float* __restrict__ mem,
                                                const float* __restrict__ cost,
                                                const float* __restrict__ sint,
                                                u16* __restrict__ Qb, u16* __restrict__ Kb,
                                                u16* __restrict__ Vtb) {
  __shared__ u16 vt[128 * 72];
  int head = blockIdx.y;
  int b = head >> 5, nh = head & 31;
  int tid = threadIdx.x;
  if (blockIdx.x < 16) {
    // ---- roped Q (scaled) + roped new-K; writes Qb, Kb[MEML..] ----
    int s0 = blockIdx.x * 64;
    const float qs = 0.08838834764831845f;  // 1/sqrt(128)
#pragma unroll
    for (int i = 0; i < 4; ++i) {
      int flat = i * 256 + tid;           // 1024 = 64 s * 16 j-groups
      int sl = flat >> 4, jg = (flat & 15) << 2;
      int s = s0 + sl;
      size_t base = ((size_t)(s * 2 + b)) * 12288 + (size_t)nh * 384;
      ushort4 q1v = *(const ushort4*)(mixed + base + jg);
      ushort4 q2v = *(const ushort4*)(mixed + base + 64 + jg);
      ushort4 k1v = *(const ushort4*)(mixed + base + 128 + jg);
      ushort4 k2v = *(const ushort4*)(mixed + base + 192 + jg);
      float4 cv = *(const float4*)(cost + s * 64 + jg);
      float4 sv = *(const float4*)(sint + s * 64 + jg);
      const u16* q1a = (const u16*)&q1v; const u16* q2a = (const u16*)&q2v;
      const u16* k1a = (const u16*)&k1v; const u16* k2a = (const u16*)&k2v;
      const float* ca = (const float*)&cv; const float* sa = (const float*)&sv;
      ushort4 qo1, qo2, ko1, ko2;
      u16* qo1a = (u16*)&qo1; u16* qo2a = (u16*)&qo2;
      u16* ko1a = (u16*)&ko1; u16* ko2a = (u16*)&ko2;
#pragma unroll
      for (int e = 0; e < 4; ++e) {
        float q1 = bf16_to_f32(q1a[e]), q2 = bf16_to_f32(q2a[e]);
        float k1 = bf16_to_f32(k1a[e]), k2 = bf16_to_f32(k2a[e]);
        float c = ca[e], sn = sa[e];
        qo1a[e] = f32_to_bf16((q1 * c - q2 * sn) * qs);
        qo2a[e] = f32_to_bf16((q2 * c + q1 * sn) * qs);
        ko1a[e] = f32_to_bf16(k1 * c - k2 * sn);
        ko2a[e] = f32_to_bf16(k2 * c + k1 * sn);
      }
      size_t qoff = ((size_t)head * SQ + s) * HD;
      *(ushort4*)(Qb + qoff + jg)      = qo1;
      *(ushort4*)(Qb + qoff + 64 + jg) = qo2;
      size_t koff = ((size_t)head * KV + MEML + s) * HD;
      *(ushort4*)(Kb + koff + jg)      = ko1;
      *(ushort4*)(Kb + koff + 64 + jg) = ko2;
    }
  } else {
    // ---- mem-K copy + V transposed; writes Kb[0..MEML), Vtb ----
    int t0 = (blockIdx.x - 16) * 64;
    if (t0 < MEML) {
#pragma unroll
      for (int i = 0; i < 8; ++i) {       // 2048 = 64 t * 32 d-groups
        int flat = i * 256 + tid;
        int tl = flat >> 5, dg = (flat & 31) << 2;
        float4 kv4 = *(const float4*)(mem + ((size_t)b * MEML + t0 + tl) * 8192 + (size_t)nh * HD + dg);
        ushort4 o;
        o.x = f32_to_bf16(kv4.x); o.y = f32_to_bf16(kv4.y);
        o.z = f32_to_bf16(kv4.z); o.w = f32_to_bf16(kv4.w);
        *(ushort4*)(Kb + ((size_t)head * KV + t0 + tl) * HD + dg) = o;
      }
    }
#pragma unroll
    for (int i = 0; i < 8; ++i) {
      int flat = i * 256 + tid;
      int tl = flat >> 5, dg = (flat & 31) << 2;
      int t = t0 + tl;
      u16 e0, e1, e2, e3;
      if (t < MEML) {
        float4 v4 = *(const float4*)(mem + ((size_t)b * MEML + t) * 8192 + 4096 + (size_t)nh * HD + dg);
        e0 = f32_to_bf16(v4.x); e1 = f32_to_bf16(v4.y);
        e2 = f32_to_bf16(v4.z); e3 = f32_to_bf16(v4.w);
      } else {
        ushort4 v4 = *(const ushort4*)(mixed + ((size_t)((t - MEML) * 2 + b)) * 12288 + (size_t)nh * 384 + 256 + dg);
        e0 = v4.x; e1 = v4.y; e2 = v4.z; e3 = v4.w;
      }
      vt[(dg + 0) * 72 + tl] = e0;
      vt[(dg + 1) * 72 + tl] = e1;
      vt[(dg + 2) * 72 + tl] = e2;
      vt[(dg + 3) * 72 + tl] = e3;
    }
    __syncthreads();
#pragma unroll
    for (int i = 0; i < 4; ++i) {
      int c = i * 256 + tid;
      int d = c >> 3, slot = c & 7;
      *(bf16x8*)(Vtb + ((size_t)head * HD + d) * KV + t0 + slot * 8) =
          *(const bf16x8*)(vt + d * 72 + slot * 8);
    }
  }
}

// ---------------- flash attention: SWAPPED-QK, lane-local softmax ----------------
__global__ __launch_bounds__(512) void attn_fwd(const u16* __restrict__ Qb, const u16* __restrict__ Kb,
                                                const u16* __restrict__ Vtb, u16* __restrict__ ctx) {
  __shared__ u16 Ks[2][64 * 128];    // [buf][t][k]; reused as T[128][128] in epilogue
  __shared__ u16 Vts[2][128 * 64];   // [buf][d][t]
  __shared__ u16 Ps[8 * 16 * 64];    // per-wave P: [s=rl row][t], XOR-swizzled
  const int tid = threadIdx.x;
  const int lane = tid & 63;
  const int w = tid >> 6;            // 0..7
  const int q0 = blockIdx.x * 128;
  const int head = blockIdx.y;
  const int rl = lane & 15, cg = lane >> 4;
  const int sglob = q0 + w * 16 + rl;   // this lane's query row

  bf16x8 qf[4];
  {
    const u16* Qrow = Qb + ((size_t)head * SQ + sglob) * HD;
#pragma unroll
    for (int kk = 0; kk < 4; ++kk)
      qf[kk] = *(const bf16x8*)(Qrow + kk * 32 + cg * 8);
  }

  f32x4 acc[8];
#pragma unroll
  for (int i = 0; i < 8; ++i) acc[i] = (f32x4){0.f, 0.f, 0.f, 0.f};
  float mrow = -3.0e38f;
  float lrow = 0.f;

  const int ntile = (MEML + q0 + 128) >> 6;   // 18..32

  auto stageKV = [&](int it) {
    int t0 = it * 64;
    int buf = it & 1;
#pragma unroll
    for (int i = 0; i < 2; ++i) {
      int flat = i * 512 + tid;
      int row = flat >> 4;
      int scb = ((flat & 15) << 4) ^ ((row & 7) << 4);
      gload_lds16((const char*)(Kb + ((size_t)head * KV + t0 + row) * HD) + scb,
                  (char*)Ks[buf] + (flat << 4));
    }
#pragma unroll
    for (int i = 0; i < 2; ++i) {
      int flat = i * 512 + tid;
      int row = flat >> 3;
      int scb = ((flat & 7) << 4) ^ ((row & 7) << 4);
      gload_lds16((const char*)(Vtb + ((size_t)head * HD + row) * KV + t0) + scb,
                  (char*)Vts[buf] + (flat << 4));
    }
  };

  stageKV(0);

  for (int it = 0; it < ntile; ++it) {
    const int t0 = it * 64;
    if (it + 1 < ntile) {
      stageKV(it + 1);
      asm volatile("s_waitcnt vmcnt(4)" ::: "memory");
    } else {
      asm volatile("s_waitcnt vmcnt(0)" ::: "memory");
    }
    __builtin_amdgcn_s_barrier();
    const char* Kbuf = (const char*)Ks[it & 1];
    const char* Vbuf = (const char*)Vts[it & 1];
    const bool live = (t0 - MEML) <= (q0 + w * 16 + 15);
    if (live) {
      // S^T = K Q^T : lane holds S[t=t0+tn*16+cg*4+j][s=sglob]
      f32x4 sf[4];
#pragma unroll
      for (int tn = 0; tn < 4; ++tn) {
        f32x4 s = (f32x4){0.f, 0.f, 0.f, 0.f};
#pragma unroll
        for (int kk = 0; kk < 4; ++kk) {
          int row = tn * 16 + rl;
          int cb = (kk * 64 + cg * 16) ^ ((row & 7) << 4);
          bf16x8 kf = *(const bf16x8*)(Kbuf + row * 256 + cb);
          s = __builtin_amdgcn_mfma_f32_16x16x32_bf16(kf, qf[kk], s, 0, 0, 0);
        }
        sf[tn] = s;
      }
      if (t0 + 63 > MEML + q0 + w * 16) {
#pragma unroll
        for (int tn = 0; tn < 4; ++tn)
#pragma unroll
          for (int j = 0; j < 4; ++j) {
            int t = t0 + tn * 16 + cg * 4 + j;
            if (t - MEML > sglob) sf[tn][j] = -40000.0f;
          }
      }
      // in-lane max over 16 t-values, then 2-shfl allreduce across cg
      float mt = sf[0][0];
#pragma unroll
      for (int tn = 0; tn < 4; ++tn)
#pragma unroll
        for (int j = 0; j < 4; ++j) mt = fmaxf(mt, sf[tn][j]);
      mt = fmaxf(mt, __shfl_xor(mt, 16, 64));
      mt = fmaxf(mt, __shfl_xor(mt, 32, 64));
      float mn = fmaxf(mrow, mt);
      float psc = __expf(mrow - mn);
      mrow = mn;
      float ls = 0.f;
#pragma unroll
      for (int tn = 0; tn < 4; ++tn) {
        ushort4 pk;
        u16* pka = (u16*)&pk;
#pragma unroll
        for (int j = 0; j < 4; ++j) {
          float p = __expf(sf[tn][j] - mn);
          ls += p;
          pka[j] = f32_to_bf16(p);
        }
        int addr = w * 2048 + rl * 128 + ((tn * 32 + cg * 8) ^ ((rl & 7) << 4));
        *(ushort4*)((char*)Ps + addr) = pk;
      }
      ls += __shfl_xor(ls, 16, 64);
      ls += __shfl_xor(ls, 32, 64);
      lrow = lrow * psc + ls;
#pragma unroll
      for (int dn = 0; dn < 8; ++dn)
#pragma unroll
        for (int j = 0; j < 4; ++j) acc[dn][j] *= psc;
      // ctx^T += V^T P^T : A=Vt rows=d, B=P rows(s)=rl
#pragma unroll
      for (int dn = 0; dn < 8; ++dn) {
#pragma unroll
        for (int kk2 = 0; kk2 < 2; ++kk2) {
          int pcb = (kk2 * 64 + cg * 16) ^ ((rl & 7) << 4);
          bf16x8 pf = *(const bf16x8*)((const char*)Ps + w * 2048 + rl * 128 + pcb);
          int vrow = dn * 16 + rl;
          int vcb = (kk2 * 64 + cg * 16) ^ ((vrow & 7) << 4);
          bf16x8 vf = *(const bf16x8*)(Vbuf + vrow * 128 + vcb);
          acc[dn] = __builtin_amdgcn_mfma_f32_16x16x32_bf16(vf, pf, acc[dn], 0, 0, 0);
        }
      }
    }
    __builtin_amdgcn_s_barrier();
  }

  // epilogue: acc holds ctx^T[d][s] -> transpose via LDS (reuse Ks, 32 KB) for
  // coalesced 16B global stores. T layout: [128 s-local][128 d] bf16, 256B rows.
  const float inv = 1.0f / lrow;
  u16* T = (u16*)Ks;
  {
    int trow = w * 16 + rl;           // trow&7 == rl&7
#pragma unroll
    for (int dn = 0; dn < 8; ++dn) {
      ushort4 pk;
      u16* pka = (u16*)&pk;
#pragma unroll
      for (int j = 0; j < 4; ++j) pka[j] = f32_to_bf16(acc[dn][j] * inv);
      int addr = trow * 256 + ((dn * 32 + cg * 8) ^ ((rl & 7) << 4));
      *(ushort4*)((char*)T + addr) = pk;
    }
  }
  asm volatile("s_waitcnt lgkmcnt(0)" ::: "memory");
  __builtin_amdgcn_s_barrier();
  const int b = head >> 5, nh = head & 31;
#pragma unroll
  for (int i = 0; i < 4; ++i) {
    int flat = i * 512 + tid;         // 2048 chunks of 16B (128 rows x 16 chunks)
    int r = flat >> 4, c = flat & 15;
    bf16x8 v = *(const bf16x8*)((const char*)T + r * 256 + ((c * 16) ^ ((r & 7) << 4)));
    *(bf16x8*)(ctx + ((size_t)((q0 + r) * 2 + b)) * H + (size_t)nh * HD + c * 8) = v;
  }
}

// ---------------- launch ----------------
extern "C" void kernel_launch(void* const* d_in, const int* in_sizes, int n_in,
                              void* d_out, int out_size, void* d_ws, size_t ws_size,
                              hipStream_t stream) {
  const float* hidden  = (const float*)d_in[0];
  const float* mem     = (const float*)d_in[3];
  const float* qkv_w   = (const float*)d_in[4];
  const float* qkv_b   = (const float*)d_in[5];
  const float* dense_w = (const float*)d_in[6];
  const float* dense_b = (const float*)d_in[7];
  float* out = (float*)d_out;
  char* ws = (char*)d_ws;

  u16* mixed = (u16*)ws;                          // [0, 50331648) bf16 2048x12288
  char* R1 = ws + 100663296;
  u16* hid_bf = (u16*)R1;                         // aliased: pre-GEMM1 use
  u16* qw_bf  = (u16*)(R1 + 16777216);            // 100 MB; consumed by gemm1
  u16* Qb  = (u16*)R1;
  u16* Kb  = (u16*)(R1 + 16777216);
  u16* Vtb = (u16*)(R1 + 50331648);
  u16* ctx = (u16*)(R1 + 83886080);
  u16* dw_bf = (u16*)(R1 + 100663296);            // overlaps qw_bf tail -> convert AFTER gemm1
  float* cost = (float*)(ws + 234881024);
  float* sint = (float*)(ws + 234881024 + 262144);

  conv2<<<57344, 256, 0, stream>>>(hidden, hid_bf, qkv_w, qw_bf);
  rope_tables<<<256, 256, 0, stream>>>(cost, sint);
  gemmT<u16, 3><<<dim3(64, 8), 512, 0, stream>>>(hid_bf, qw_bf, qkv_b, mixed, 12288, 4096);
  conv_bf16<<<16384, 256, 0, stream>>>(dense_w, dw_bf, 4194304);   // after gemm1 (alias!)
  prep_all<<<dim3(48, 64), 256, 0, stream>>>(mixed, mem, cost, sint, Qb, Kb, Vtb);
  attn_fwd<<<dim3(8, 64), 512, 0, stream>>>(Qb, Kb, Vtb, ctx);
  gemmT<float, 2><<<dim3(32, 8), 512, 0, stream>>>(ctx, dw_bf, dense_b, out, 4096, 4096);
}

// Round 16
// 480.505 us; speedup vs baseline: 1.0253x; 1.0095x over previous
//
#include <hip/hip_runtime.h>

// SelfAttention (Transformer-XL style) on gfx950. r16 = r15 + T13 defer-max in attn
// + conv(dense_w) merged into prep_all (ordering: after gemm1, before gemm2).
// conv2 (hidden+qkv_w fused), gemmT NF=3 (qkv), merged preps+dense-conv,
// flash attn (swapped-QK lane-local softmax, defer-max), gemmT NF=2 (dense).

typedef __attribute__((ext_vector_type(4))) float f32x4;
typedef __attribute__((ext_vector_type(8))) short bf16x8;
typedef unsigned short u16;

#define SQ   1024
#define BSZ  2
#define H    4096
#define NH   32
#define HD   128
#define MEML 1024
#define KV   2048

__device__ __forceinline__ u16 f32_to_bf16(float f) {
  union { float f; unsigned int u; } v; v.f = f;
  unsigned int r = v.u + 0x7FFFu + ((v.u >> 16) & 1u);
  return (u16)(r >> 16);
}
__device__ __forceinline__ float bf16_to_f32(u16 x) {
  union { unsigned int u; float f; } v; v.u = ((unsigned int)x) << 16; return v.f;
}

__device__ __forceinline__ void gload_lds16(const void* g, void* l) {
  __builtin_amdgcn_global_load_lds((const __attribute__((address_space(1))) void*)g,
                                   (__attribute__((address_space(3))) void*)l, 16, 0, 0);
}

// ---------------- fused f32 -> bf16 convert (hidden + qkv_w only) ----------------
// dense_w NOT here: dw_bf aliases qw_bf tail; converted in prep_all AFTER gemm1.
#define NA4 2097152
#define NB4 12582912
__global__ __launch_bounds__(256) void conv2(const float* __restrict__ a, u16* __restrict__ oa,
                                             const float* __restrict__ bsrc, u16* __restrict__ ob) {
  int idx = blockIdx.x * 256 + threadIdx.x;
  const float* s; u16* o; int off;
  if (idx < NA4) { s = a;    o = oa; off = idx; }
  else           { s = bsrc; o = ob; off = idx - NA4; }
  float4 v = ((const float4*)s)[off];
  ushort4 r;
  r.x = f32_to_bf16(v.x); r.y = f32_to_bf16(v.y);
  r.z = f32_to_bf16(v.z); r.w = f32_to_bf16(v.w);
  ((ushort4*)o)[off] = r;
}

// ---------------- RoPE tables ----------------
__global__ __launch_bounds__(256) void rope_tables(float* __restrict__ cost, float* __restrict__ sint) {
  int idx = blockIdx.x * 256 + threadIdx.x;   // 65536 = 1024 s * 64 j
  int s = idx >> 6, j = idx & 63;
  float inv = powf(10000.0f, -(float)j / 64.0f);
  float ang = (float)(MEML + s) * inv;
  cost[idx] = cosf(ang);
  sint[idx] = sinf(ang);
}

// ---------------- GEMM: C[M,N] = A[M,K](bf16) * B[N,K]^T(bf16) + bias[N] ----------
// BM=256, BN=NF*64, BK=64; 512 threads = 8 waves (2M x 4N), per-wave 128 x NF*16.
// 4 phases/K-tile; 8KiB stage units; counted vmcnt(NF) once per tile.
template <typename OUT_T, int NF>
__global__ __launch_bounds__(512, 2) void gemmT(const u16* __restrict__ A, const u16* __restrict__ B,
                                                const float* __restrict__ bias, OUT_T* __restrict__ C,
                                                int N, int K) {
  constexpr int WN = NF * 16;                 // per-wave N width
  constexpr int NH0 = (NF + 1) / 2;           // frags in set0
  constexpr int SB2 = NF - (NF >> 1);         // B units staged at ph2
  __shared__ char lds[2][32768 + NF * 8192];  // A rows 0..255 @0, B rows @32768
  const int tid = threadIdx.x;
  const int lane = tid & 63;
  const int w = tid >> 6;
  const int wm = w >> 2, wn = w & 3;
  const int rl = lane & 15, cg = lane >> 4;
  const int m0 = blockIdx.y * 256, n0 = blockIdx.x * (NF * 64);
  const int nt = K >> 6;

  const int srow = tid >> 3;                              // 0..63 (unit-local row)
  const int scb = ((tid & 7) << 4) ^ ((srow & 7) << 4);   // pre-swizzled source byte col

  auto stage_a = [&](int tile, int ua) {
    if (tile >= nt) return;
    gload_lds16((const char*)(A + (size_t)(m0 + ua * 64 + srow) * K + (size_t)tile * 64) + scb,
                lds[tile & 1] + ua * 8192 + tid * 16);
  };
  auto stage_b = [&](int tile, int ub) {
    if (tile >= nt) return;
    gload_lds16((const char*)(B + (size_t)(n0 + ub * 64 + srow) * K + (size_t)tile * 64) + scb,
                lds[tile & 1] + 32768 + ub * 8192 + tid * 16);
  };

  f32x4 acc[8][NF];
#pragma unroll
  for (int i = 0; i < 8; ++i)
#pragma unroll
    for (int j = 0; j < NF; ++j) acc[i][j] = (f32x4){0.f, 0.f, 0.f, 0.f};

  bf16x8 af[4][2], bf[NF][2];

  auto read_a = [&](const char* buf, int mh) {
#pragma unroll
    for (int mi = 0; mi < 4; ++mi) {
      int R = wm * 128 + mh * 64 + mi * 16 + rl;
#pragma unroll
      for (int kk = 0; kk < 2; ++kk) {
        int cb = (kk * 64 + cg * 16) ^ ((R & 7) << 4);
        af[mi][kk] = *(const bf16x8*)(buf + R * 128 + cb);
      }
    }
  };
  auto read_b1 = [&](const char* buf, int nl) {
    int R = wn * WN + nl * 16 + rl;
#pragma unroll
    for (int kk = 0; kk < 2; ++kk) {
      int cb = (kk * 64 + cg * 16) ^ ((R & 7) << 4);
      bf[nl][kk] = *(const bf16x8*)(buf + 32768 + R * 128 + cb);
    }
  };
  auto mfset = [&](int mh, int lo, int hi) {
    __builtin_amdgcn_s_setprio(1);
#pragma unroll
    for (int kk = 0; kk < 2; ++kk)
#pragma unroll
      for (int mi = 0; mi < 4; ++mi)
#pragma unroll
        for (int nl = 0; nl < NF; ++nl)
          if (nl >= lo && nl < hi)
            acc[mh * 4 + mi][nl] = __builtin_amdgcn_mfma_f32_16x16x32_bf16(
                af[mi][kk], bf[nl][kk], acc[mh * 4 + mi][nl], 0, 0, 0);
    __builtin_amdgcn_s_setprio(0);
  };

  // prologue: tile0 A+B, tile1 B; wait tile0 landed (tile1.B = NF outstanding)
#pragma unroll
  for (int ua = 0; ua < 4; ++ua) stage_a(0, ua);
#pragma unroll
  for (int ub = 0; ub < NF; ++ub) stage_b(0, ub);
#pragma unroll
  for (int ub = 0; ub < NF; ++ub) stage_b(1, ub);
  if (NF == 2)      { asm volatile("s_waitcnt vmcnt(2)" ::: "memory"); }
  else if (NF == 3) { asm volatile("s_waitcnt vmcnt(3)" ::: "memory"); }
  else              { asm volatile("s_waitcnt vmcnt(4)" ::: "memory"); }
  __builtin_amdgcn_s_barrier();

  for (int kt = 0; kt < nt; ++kt) {
    const char* buf = lds[kt & 1];
    // ph0: quadrant (mh0,set0); stage (kt+1).A units 0,1 -> p^1
    read_a(buf, 0);
#pragma unroll
    for (int nl = 0; nl < NH0; ++nl) read_b1(buf, nl);
    stage_a(kt + 1, 0); stage_a(kt + 1, 1);
    __builtin_amdgcn_s_barrier();
    asm volatile("s_waitcnt lgkmcnt(0)" ::: "memory");
    mfset(0, 0, NH0);
    __builtin_amdgcn_s_barrier();
    // ph1: quadrant (mh0,set1); stage (kt+1).A units 2,3 -> p^1
#pragma unroll
    for (int nl = NH0; nl < NF; ++nl) read_b1(buf, nl);
    stage_a(kt + 1, 2); stage_a(kt + 1, 3);
    __builtin_amdgcn_s_barrier();
    asm volatile("s_waitcnt lgkmcnt(0)" ::: "memory");
    mfset(0, NH0, NF);
    __builtin_amdgcn_s_barrier();
    // ph2: quadrant (mh1,set1); stage (kt+2).B units 0..SB2-1 -> p
    read_a(buf, 1);
#pragma unroll
    for (int ub = 0; ub < SB2; ++ub) stage_b(kt + 2, ub);
    __builtin_amdgcn_s_barrier();
    asm volatile("s_waitcnt lgkmcnt(0)" ::: "memory");
    mfset(1, NH0, NF);
    __builtin_amdgcn_s_barrier();
    // ph3: quadrant (mh1,set0); stage (kt+2).B units SB2..NF-1 -> p; counted vmcnt
#pragma unroll
    for (int ub = SB2; ub < NF; ++ub) stage_b(kt + 2, ub);
    __builtin_amdgcn_s_barrier();
    mfset(1, 0, NH0);
    if (kt + 2 < nt) {
      if (NF == 2)      { asm volatile("s_waitcnt vmcnt(2)" ::: "memory"); }
      else if (NF == 3) { asm volatile("s_waitcnt vmcnt(3)" ::: "memory"); }
      else              { asm volatile("s_waitcnt vmcnt(4)" ::: "memory"); }
    } else if (kt + 1 < nt) {
      asm volatile("s_waitcnt vmcnt(0)" ::: "memory");
    }
    __builtin_amdgcn_s_barrier();
  }

  // epilogue: C layout col=lane&15, row=(lane>>4)*4+j
#pragma unroll
  for (int ni = 0; ni < NF; ++ni) {
    int col = n0 + wn * WN + ni * 16 + rl;
    float bv = bias[col];
#pragma unroll
    for (int mi = 0; mi < 8; ++mi) {
      int rbase = m0 + wm * 128 + mi * 16 + cg * 4;
#pragma unroll
      for (int j = 0; j < 4; ++j) {
        float v = acc[mi][ni][j] + bv;
        if constexpr (sizeof(OUT_T) == 2)
          C[(size_t)(rbase + j) * N + col] = (OUT_T)f32_to_bf16(v);
        else
          C[(size_t)(rbase + j) * N + col] = (OUT_T)v;
      }
    }
  }
}

// ---- merged prep: x<16 roped Q/K; 16<=x<48 mem-K+Vt; x>=48 dense_w conversion ----
__global__ __launch_bounds__(256) void prep_all(const u16* __restrict__ mixed,
                                                const float* __restrict__ mem,
                                                const float* __restrict__ cost,
                                                const float* __restrict__ sint,
                                                u16* __restrict__ Qb, u16* __restrict__ Kb,
                                                u16* __restrict__ Vtb,
                                                const float* __restrict__ dw,
                                                u16* __restrict__ dw_bf) {
  __shared__ u16 vt[128 * 72];
  int head = blockIdx.y;
  int b = head >> 5, nh = head & 31;
  int tid = threadIdx.x;
  if (blockIdx.x >= 48) {
    // ---- dense_w f32->bf16: 1024 blocks x 4096 float4 (runs after gemm1; alias-safe) ----
    int base = (((blockIdx.x - 48) << 6) + head) << 12;   // *4096
#pragma unroll
    for (int i = 0; i < 16; ++i) {
      int idx = base + i * 256 + tid;
      float4 v = ((const float4*)dw)[idx];
      ushort4 r;
      r.x = f32_to_bf16(v.x); r.y = f32_to_bf16(v.y);
      r.z = f32_to_bf16(v.z); r.w = f32_to_bf16(v.w);
      ((ushort4*)dw_bf)[idx] = r;
    }
  } else if (blockIdx.x < 16) {
    // ---- roped Q (scaled) + roped new-K; writes Qb, Kb[MEML..] ----
    int s0 = blockIdx.x * 64;
    const float qs = 0.08838834764831845f;  // 1/sqrt(128)
#pragma unroll
    for (int i = 0; i < 4; ++i) {
      int flat = i * 256 + tid;           // 1024 = 64 s * 16 j-groups
      int sl = flat >> 4, jg = (flat & 15) << 2;
      int s = s0 + sl;
      size_t base = ((size_t)(s * 2 + b)) * 12288 + (size_t)nh * 384;
      ushort4 q1v = *(const ushort4*)(mixed + base + jg);
      ushort4 q2v = *(const ushort4*)(mixed + base + 64 + jg);
      ushort4 k1v = *(const ushort4*)(mixed + base + 128 + jg);
      ushort4 k2v = *(const ushort4*)(mixed + base + 192 + jg);
      float4 cv = *(const float4*)(cost + s * 64 + jg);
      float4 sv = *(const float4*)(sint + s * 64 + jg);
      const u16* q1a = (const u16*)&q1v; const u16* q2a = (const u16*)&q2v;
      const u16* k1a = (const u16*)&k1v; const u16* k2a = (const u16*)&k2v;
      const float* ca = (const float*)&cv; const float* sa = (const float*)&sv;
      ushort4 qo1, qo2, ko1, ko2;
      u16* qo1a = (u16*)&qo1; u16* qo2a = (u16*)&qo2;
      u16* ko1a = (u16*)&ko1; u16* ko2a = (u16*)&ko2;
#pragma unroll
      for (int e = 0; e < 4; ++e) {
        float q1 = bf16_to_f32(q1a[e]), q2 = bf16_to_f32(q2a[e]);
        float k1 = bf16_to_f32(k1a[e]), k2 = bf16_to_f32(k2a[e]);
        float c = ca[e], sn = sa[e];
        qo1a[e] = f32_to_bf16((q1 * c - q2 * sn) * qs);
        qo2a[e] = f32_to_bf16((q2 * c + q1 * sn) * qs);
        ko1a[e] = f32_to_bf16(k1 * c - k2 * sn);
        ko2a[e] = f32_to_bf16(k2 * c + k1 * sn);
      }
      size_t qoff = ((size_t)head * SQ + s) * HD;
      *(ushort4*)(Qb + qoff + jg)      = qo1;
      *(ushort4*)(Qb + qoff + 64 + jg) = qo2;
      size_t koff = ((size_t)head * KV + MEML + s) * HD;
      *(ushort4*)(Kb + koff + jg)      = ko1;
      *(ushort4*)(Kb + koff + 64 + jg) = ko2;
    }
  } else {
    // ---- mem-K copy + V transposed; writes Kb[0..MEML), Vtb ----
    int t0 = (blockIdx.x - 16) * 64;
    if (t0 < MEML) {
#pragma unroll
      for (int i = 0; i < 8; ++i) {       // 2048 = 64 t * 32 d-groups
        int flat = i * 256 + tid;
        int tl = flat >> 5, dg = (flat & 31) << 2;
        float4 kv4 = *(const float4*)(mem + ((size_t)b * MEML + t0 + tl) * 8192 + (size_t)nh * HD + dg);
        ushort4 o;
        o.x = f32_to_bf16(kv4.x); o.y = f32_to_bf16(kv4.y);
        o.z = f32_to_bf16(kv4.z); o.w = f32_to_bf16(kv4.w);
        *(ushort4*)(Kb + ((size_t)head * KV + t0 + tl) * HD + dg) = o;
      }
    }
#pragma unroll
    for (int i = 0; i < 8; ++i) {
      int flat = i * 256 + tid;
      int tl = flat >> 5, dg = (flat & 31) << 2;
      int t = t0 + tl;
      u16 e0, e1, e2, e3;
      if (t < MEML) {
        float4 v4 = *(const float4*)(mem + ((size_t)b * MEML + t) * 8192 + 4096 + (size_t)nh * HD + dg);
        e0 = f32_to_bf16(v4.x); e1 = f32_to_bf16(v4.y);
        e2 = f32_to_bf16(v4.z); e3 = f32_to_bf16(v4.w);
      } else {
        ushort4 v4 = *(const ushort4*)(mixed + ((size_t)((t - MEML) * 2 + b)) * 12288 + (size_t)nh * 384 + 256 + dg);
        e0 = v4.x; e1 = v4.y; e2 = v4.z; e3 = v4.w;
      }
      vt[(dg + 0) * 72 + tl] = e0;
      vt[(dg + 1) * 72 + tl] = e1;
      vt[(dg + 2) * 72 + tl] = e2;
      vt[(dg + 3) * 72 + tl] = e3;
    }
    __syncthreads();
#pragma unroll
    for (int i = 0; i < 4; ++i) {
      int c = i * 256 + tid;
      int d = c >> 3, slot = c & 7;
      *(bf16x8*)(Vtb + ((size_t)head * HD + d) * KV + t0 + slot * 8) =
          *(const bf16x8*)(vt + d * 72 + slot * 8);
    }
  }
}

// ---------------- flash attention: SWAPPED-QK, lane-local softmax, defer-max ------
__global__ __launch_bounds__(512) void attn_fwd(const u16* __restrict__ Qb, const u16* __restrict__ Kb,
                                                const u16* __restrict__ Vtb, u16* __restrict__ ctx) {
  __shared__ u16 Ks[2][64 * 128];    // [buf][t][k]; reused as T[128][128] in epilogue
  __shared__ u16 Vts[2][128 * 64];   // [buf][d][t]
  __shared__ u16 Ps[8 * 16 * 64];    // per-wave P: [s=rl row][t], XOR-swizzled
  const int tid = threadIdx.x;
  const int lane = tid & 63;
  const int w = tid >> 6;            // 0..7
  const int q0 = blockIdx.x * 128;
  const int head = blockIdx.y;
  const int rl = lane & 15, cg = lane >> 4;
  const int sglob = q0 + w * 16 + rl;   // this lane's query row

  bf16x8 qf[4];
  {
    const u16* Qrow = Qb + ((size_t)head * SQ + sglob) * HD;
#pragma unroll
    for (int kk = 0; kk < 4; ++kk)
      qf[kk] = *(const bf16x8*)(Qrow + kk * 32 + cg * 8);
  }

  f32x4 acc[8];
#pragma unroll
  for (int i = 0; i < 8; ++i) acc[i] = (f32x4){0.f, 0.f, 0.f, 0.f};
  float mrow = -3.0e38f;
  float lrow = 0.f;

  const int ntile = (MEML + q0 + 128) >> 6;   // 18..32

  auto stageKV = [&](int it) {
    int t0 = it * 64;
    int buf = it & 1;
#pragma unroll
    for (int i = 0; i < 2; ++i) {
      int flat = i * 512 + tid;
      int row = flat >> 4;
      int scb = ((flat & 15) << 4) ^ ((row & 7) << 4);
      gload_lds16((const char*)(Kb + ((size_t)head * KV + t0 + row) * HD) + scb,
                  (char*)Ks[buf] + (flat << 4));
    }
#pragma unroll
    for (int i = 0; i < 2; ++i) {
      int flat = i * 512 + tid;
      int row = flat >> 3;
      int scb = ((flat & 7) << 4) ^ ((row & 7) << 4);
      gload_lds16((const char*)(Vtb + ((size_t)head * HD + row) * KV + t0) + scb,
                  (char*)Vts[buf] + (flat << 4));
    }
  };

  stageKV(0);

  for (int it = 0; it < ntile; ++it) {
    const int t0 = it * 64;
    if (it + 1 < ntile) {
      stageKV(it + 1);
      asm volatile("s_waitcnt vmcnt(4)" ::: "memory");
    } else {
      asm volatile("s_waitcnt vmcnt(0)" ::: "memory");
    }
    __builtin_amdgcn_s_barrier();
    const char* Kbuf = (const char*)Ks[it & 1];
    const char* Vbuf = (const char*)Vts[it & 1];
    const bool live = (t0 - MEML) <= (q0 + w * 16 + 15);
    if (live) {
      // S^T = K Q^T : lane holds S[t=t0+tn*16+cg*4+j][s=sglob]
      f32x4 sf[4];
#pragma unroll
      for (int tn = 0; tn < 4; ++tn) {
        f32x4 s = (f32x4){0.f, 0.f, 0.f, 0.f};
#pragma unroll
        for (int kk = 0; kk < 4; ++kk) {
          int row = tn * 16 + rl;
          int cb = (kk * 64 + cg * 16) ^ ((row & 7) << 4);
          bf16x8 kf = *(const bf16x8*)(Kbuf + row * 256 + cb);
          s = __builtin_amdgcn_mfma_f32_16x16x32_bf16(kf, qf[kk], s, 0, 0, 0);
        }
        sf[tn] = s;
      }
      if (t0 + 63 > MEML + q0 + w * 16) {
#pragma unroll
        for (int tn = 0; tn < 4; ++tn)
#pragma unroll
          for (int j = 0; j < 4; ++j) {
            int t = t0 + tn * 16 + cg * 4 + j;
            if (t - MEML > sglob) sf[tn][j] = -40000.0f;
          }
      }
      // in-lane max over 16 t-values, then 2-shfl allreduce across cg
      float mt = sf[0][0];
#pragma unroll
      for (int tn = 0; tn < 4; ++tn)
#pragma unroll
        for (int j = 0; j < 4; ++j) mt = fmaxf(mt, sf[tn][j]);
      mt = fmaxf(mt, __shfl_xor(mt, 16, 64));
      mt = fmaxf(mt, __shfl_xor(mt, 32, 64));
      // T13 defer-max: skip rescale when max growth <= 8 (P bounded by e^8)
      if (!__all(mt <= mrow + 8.0f)) {
        float mn = fmaxf(mrow, mt);
        float psc = __expf(mrow - mn);
        mrow = mn;
        lrow *= psc;
#pragma unroll
        for (int dn = 0; dn < 8; ++dn)
#pragma unroll
          for (int j = 0; j < 4; ++j) acc[dn][j] *= psc;
      }
      float ls = 0.f;
#pragma unroll
      for (int tn = 0; tn < 4; ++tn) {
        ushort4 pk;
        u16* pka = (u16*)&pk;
#pragma unroll
        for (int j = 0; j < 4; ++j) {
          float p = __expf(sf[tn][j] - mrow);
          ls += p;
          pka[j] = f32_to_bf16(p);
        }
        int addr = w * 2048 + rl * 128 + ((tn * 32 + cg * 8) ^ ((rl & 7) << 4));
        *(ushort4*)((char*)Ps + addr) = pk;
      }
      ls += __shfl_xor(ls, 16, 64);
      ls += __shfl_xor(ls, 32, 64);
      lrow += ls;
      // ctx^T += V^T P^T : A=Vt rows=d, B=P rows(s)=rl
#pragma unroll
      for (int dn = 0; dn < 8; ++dn) {
#pragma unroll
        for (int kk2 = 0; kk2 < 2; ++kk2) {
          int pcb = (kk2 * 64 + cg * 16) ^ ((rl & 7) << 4);
          bf16x8 pf = *(const bf16x8*)((const char*)Ps + w * 2048 + rl * 128 + pcb);
          int vrow = dn * 16 + rl;
          int vcb = (kk2 * 64 + cg * 16) ^ ((vrow & 7) << 4);
          bf16x8 vf = *(const bf16x8*)(Vbuf + vrow * 128 + vcb);
          acc[dn] = __builtin_amdgcn_mfma_f32_16x16x32_bf16(vf, pf, acc[dn], 0, 0, 0);
        }
      }
    }
    __builtin_amdgcn_s_barrier();
  }

  // epilogue: acc holds ctx^T[d][s] -> transpose via LDS (reuse Ks, 32 KB) for
  // coalesced 16B global stores. T layout: [128 s-local][128 d] bf16, 256B rows.
  const float inv = 1.0f / lrow;
  u16* T = (u16*)Ks;
  {
    int trow = w * 16 + rl;           // trow&7 == rl&7
#pragma unroll
    for (int dn = 0; dn < 8; ++dn) {
      ushort4 pk;
      u16* pka = (u16*)&pk;
#pragma unroll
      for (int j = 0; j < 4; ++j) pka[j] = f32_to_bf16(acc[dn][j] * inv);
      int addr = trow * 256 + ((dn * 32 + cg * 8) ^ ((rl & 7) << 4));
      *(ushort4*)((char*)T + addr) = pk;
    }
  }
  asm volatile("s_waitcnt lgkmcnt(0)" ::: "memory");
  __builtin_amdgcn_s_barrier();
  const int b = head >> 5, nh = head & 31;
#pragma unroll
  for (int i = 0; i < 4; ++i) {
    int flat = i * 512 + tid;         // 2048 chunks of 16B (128 rows x 16 chunks)
    int r = flat >> 4, c = flat & 15;
    bf16x8 v = *(const bf16x8*)((const char*)T + r * 256 + ((c * 16) ^ ((r & 7) << 4)));
    *(bf16x8*)(ctx + ((size_t)((q0 + r) * 2 + b)) * H + (size_t)nh * HD + c * 8) = v;
  }
}

// ---------------- launch ----------------
extern "C" void kernel_launch(void* const* d_in, const int* in_sizes, int n_in,
                              void* d_out, int out_size, void* d_ws, size_t ws_size,
                              hipStream_t stream) {
  const float* hidden  = (const float*)d_in[0];
  const float* mem     = (const float*)d_in[3];
  const float* qkv_w   = (const float*)d_in[4];
  const float* qkv_b   = (const float*)d_in[5];
  const float* dense_w = (const float*)d_in[6];
  const float* dense_b = (const float*)d_in[7];
  float* out = (float*)d_out;
  char* ws = (char*)d_ws;

  u16* mixed = (u16*)ws;                          // [0, 50331648) bf16 2048x12288
  char* R1 = ws + 100663296;
  u16* hid_bf = (u16*)R1;                         // aliased: pre-GEMM1 use
  u16* qw_bf  = (u16*)(R1 + 16777216);            // 100 MB; consumed by gemm1
  u16* Qb  = (u16*)R1;
  u16* Kb  = (u16*)(R1 + 16777216);
  u16* Vtb = (u16*)(R1 + 50331648);
  u16* ctx = (u16*)(R1 + 83886080);
  u16* dw_bf = (u16*)(R1 + 100663296);            // overlaps qw_bf tail -> convert AFTER gemm1
  float* cost = (float*)(ws + 234881024);
  float* sint = (float*)(ws + 234881024 + 262144);

  conv2<<<57344, 256, 0, stream>>>(hidden, hid_bf, qkv_w, qw_bf);
  rope_tables<<<256, 256, 0, stream>>>(cost, sint);
  gemmT<u16, 3><<<dim3(64, 8), 512, 0, stream>>>(hid_bf, qw_bf, qkv_b, mixed, 12288, 4096);
  prep_all<<<dim3(64, 64), 256, 0, stream>>>(mixed, mem, cost, sint, Qb, Kb, Vtb,
                                             dense_w, dw_bf);
  attn_fwd<<<dim3(8, 64), 512, 0, stream>>>(Qb, Kb, Vtb, ctx);
  gemmT<float, 2><<<dim3(32, 8), 512, 0, stream>>>(ctx, dw_bf, dense_b, out, 4096, 4096);
}